// Round 1
// baseline (4915.886 us; speedup 1.0000x reference)
//
#include <hip/hip_runtime.h>
#include <hip/hip_fp16.h>

// Problem constants
// N=512, C=3, T=300, V=25, M=2, F=C*V*M=150, H=100, gates=4H=400
// x element (n,c,t,v,m) at n*45000 + c*15000 + t*50 + (v*2+m); xs[n][t][f], f=c*50+(v*2+m)

// ws layout (float slots). Thread->gate-row map: r(t) = (t&3)*100 + (t>>2), t<400.
#define OFF_W2T   0          // [100][512]  dec folded: Whh + Wih@fcW   (transposed, thread-indexed)
#define OFF_WDT   51200      // [100][512]  dec Whh (step-1 weights)
#define OFF_WET   102400     // [100][512]  enc Whh
#define OFF_PIH   153600     // [75][512]   enc Wih as packed f16 pairs (uint32)
#define OFF_BENC  192000     // [512]       enc bih+bhh
#define OFF_B1    192512     // [512]       dec bih+bhh (step 1: input is zeros)
#define OFF_BEFF  193024     // [512]       dec bih+bhh + Wih@fcb (steps 2..299)
#define OFF_FCWT  193536     // [100][192]  fcW transposed, padded
#define OFF_HIST  212736     // __half hist[299][512][100]  (30.6 MB)
// total ws: 212736*4 + 15308800*2 = 31.5 MB

__device__ __forceinline__ float fast_sig(float x) {
  float e = __builtin_amdgcn_exp2f(x * -1.442695040888963f);   // e^-x
  return __builtin_amdgcn_rcpf(1.f + e);
}
__device__ __forceinline__ float fast_tanh(float x) {
  float e = __builtin_amdgcn_exp2f(x * -2.885390081777926f);   // e^-2x
  return fmaf(2.f, __builtin_amdgcn_rcpf(1.f + e), -1.f);      // 2*sigmoid(2x)-1
}

// shared LSTM cell tail: gates of cell j live in lanes 4j..4j+3 (types i,f,g,o)
__device__ __forceinline__ float lstm_tail(float acc, int ty, float& c) {
  float v1 = __shfl_xor(acc, 1);
  float v2 = __shfl_xor(acc, 2);
  float v3 = __shfl_xor(v1, 2);
  float d0 = acc;
  // gate q's pre-activation came from lane with type q, i.e. xor-distance ty^q
  float iv = (ty==0)?d0:(ty==1)?v1:(ty==2)?v2:v3;
  float fv = (ty==1)?d0:(ty==0)?v1:(ty==3)?v2:v3;
  float gv = (ty==2)?d0:(ty==3)?v1:(ty==0)?v2:v3;
  float ov = (ty==3)?d0:(ty==2)?v1:(ty==1)?v2:v3;
  float fi = fast_sig(iv), ff = fast_sig(fv), fo = fast_sig(ov);
  float fg = fast_tanh(gv);
  c = fmaf(ff, c, fi * fg);
  return fo * fast_tanh(c);
}

// ---------------- prep: fold decoder weights, transpose for coalesced loads ----------------
__global__ void prep(const float* __restrict__ dWih, const float* __restrict__ dWhh,
                     const float* __restrict__ dbih, const float* __restrict__ dbhh,
                     const float* __restrict__ eWih, const float* __restrict__ eWhh,
                     const float* __restrict__ ebih, const float* __restrict__ ebhh,
                     const float* __restrict__ fcW,  const float* __restrict__ fcb,
                     float* __restrict__ ws)
{
  int idx = blockIdx.x * 256 + threadIdx.x;
  if (idx < 51200) {                       // W2T / WdT / WeT
    int j = idx >> 9, t = idx & 511;
    float w2 = 0.f, wd = 0.f, we = 0.f;
    if (t < 400) {
      int r = (t & 3) * 100 + (t >> 2);
      float s = dWhh[r * 100 + j];
      float acc = 0.f;
      for (int f = 0; f < 150; ++f) acc = fmaf(dWih[r * 150 + f], fcW[f * 100 + j], acc);
      w2 = s + acc; wd = s; we = eWhh[r * 100 + j];
    }
    ws[OFF_W2T + idx] = w2; ws[OFF_WDT + idx] = wd; ws[OFF_WET + idx] = we;
  } else if (idx < 51200 + 38400) {        // packed f16 enc_Wih
    int k = idx - 51200; int d = k >> 9, t = k & 511;
    unsigned pk = 0;
    if (t < 400) {
      int r = (t & 3) * 100 + (t >> 2);
      unsigned lo = __half_as_ushort(__float2half(eWih[r * 150 + 2 * d]));
      unsigned hi = __half_as_ushort(__float2half(eWih[r * 150 + 2 * d + 1]));
      pk = lo | (hi << 16);
    }
    ((unsigned*)ws)[OFF_PIH + k] = pk;
  } else if (idx < 51200 + 38400 + 512) {  // biases
    int t = idx - (51200 + 38400);
    float be = 0.f, b1 = 0.f, bf = 0.f;
    if (t < 400) {
      int r = (t & 3) * 100 + (t >> 2);
      be = ebih[r] + ebhh[r];
      b1 = dbih[r] + dbhh[r];
      float acc = 0.f;
      for (int f = 0; f < 150; ++f) acc = fmaf(dWih[r * 150 + f], fcb[f], acc);
      bf = b1 + acc;
    }
    ws[OFF_BENC + t] = be; ws[OFF_B1 + t] = b1; ws[OFF_BEFF + t] = bf;
  } else if (idx < 51200 + 38400 + 512 + 19200) {  // fcW transposed
    int k = idx - (51200 + 38400 + 512);
    int j = k / 192, f = k % 192;
    ws[OFF_FCWT + k] = (f < 150) ? fcW[f * 100 + j] : 0.f;
  }
}

// ---------------- persistent recurrence: 1 sample per block, 599 steps ----------------
__global__ __launch_bounds__(512, 1)
void recurrent(const float* __restrict__ x, float* __restrict__ ws)
{
  const int t  = threadIdx.x;
  const int n  = blockIdx.x;
  const int j  = t >> 2, ty = t & 3;
  const bool leader = (t < 400) && (ty == 0);
  __shared__ float hbuf[2][112];

  unsigned wih[75];         // enc Wih row, f16-packed
  float    whh[100];        // current recurrent weight row (fp32)
  const unsigned* pih = ((const unsigned*)ws) + OFF_PIH;
#pragma unroll
  for (int d = 0; d < 75; ++d) wih[d] = pih[(d << 9) + t];
#pragma unroll
  for (int k = 0; k < 100; ++k) whh[k] = ws[OFF_WET + (k << 9) + t];

  const float benc  = ws[OFF_BENC + t];
  const float b1g   = ws[OFF_B1   + t];
  const float beffg = ws[OFF_BEFF + t];
  const float* xb = x + n * 45000;
  __half* histn = ((__half*)(ws + OFF_HIST)) + n * 100;
  float c = 0.f;

  // ---- encoder: 300 steps, gates = Wih@x_t + Whh@h + b ----
  for (int ts = 0; ts < 300; ++ts) {
    const int rd = ts & 1, wr = rd ^ 1;
    float acc = benc;
    if (ts > 0) {
#pragma unroll
      for (int k = 0; k < 100; k += 4) {
        float4 h4 = *(const float4*)&hbuf[rd][k];
        acc = fmaf(whh[k+0], h4.x, acc);
        acc = fmaf(whh[k+1], h4.y, acc);
        acc = fmaf(whh[k+2], h4.z, acc);
        acc = fmaf(whh[k+3], h4.w, acc);
      }
    }
    // x part: uniform (scalar) loads broadcast through SGPRs; f16 weights
#pragma unroll
    for (int c3 = 0; c3 < 3; ++c3) {
      const float* xp = xb + c3 * 15000 + ts * 50;
#pragma unroll
      for (int k = 0; k < 50; ++k) {
        const int m = c3 * 50 + k;
        unsigned u = wih[m >> 1];
        unsigned short us = (m & 1) ? (unsigned short)(u >> 16) : (unsigned short)(u & 0xffffu);
        acc = fmaf(__half2float(__ushort_as_half(us)), xp[k], acc);
      }
    }
    float hn = lstm_tail(acc, ty, c);
    if (leader) hbuf[wr][j] = hn;
    __syncthreads();
  }

  // ---- decoder: step 1 uses plain Whh (input was zeros), steps 2.. use folded W2 ----
#pragma unroll
  for (int k = 0; k < 100; ++k) whh[k] = ws[OFF_WDT + (k << 9) + t];
  for (int s = 1; s <= 299; ++s) {
    const int rd = (299 + s) & 1, wr = rd ^ 1;
    float acc = (s == 1) ? b1g : beffg;
#pragma unroll
    for (int k = 0; k < 100; k += 4) {
      float4 h4 = *(const float4*)&hbuf[rd][k];
      acc = fmaf(whh[k+0], h4.x, acc);
      acc = fmaf(whh[k+1], h4.y, acc);
      acc = fmaf(whh[k+2], h4.z, acc);
      acc = fmaf(whh[k+3], h4.w, acc);
    }
    float hn = lstm_tail(acc, ty, c);
    if (leader) {
      hbuf[wr][j] = hn;
      histn[(s - 1) * 51200 + j] = __float2half(hn);
    }
    __syncthreads();
    if (s == 1) {
#pragma unroll
      for (int k = 0; k < 100; ++k) whh[k] = ws[OFF_W2T + (k << 9) + t];
    }
  }
}

// ---------------- emit: out[n,t,f] = fcW@h_hist + fcb, t=0 slice zeroed ----------------
__global__ __launch_bounds__(192)
void emit(const float* __restrict__ ws, const float* __restrict__ fcb, float* __restrict__ out)
{
  const int f = threadIdx.x;
  const int n = blockIdx.x;
  const int z = blockIdx.y;
  float fw[100];
#pragma unroll
  for (int jj = 0; jj < 100; ++jj) fw[jj] = ws[OFF_FCWT + jj * 192 + f];
  const bool on = f < 150;
  const float bias = on ? fcb[f] : 0.f;
  const int cc = f / 50, r = f % 50;
  float* ob = out + n * 45000 + cc * 15000 + r;
  const __half* hist = (const __half*)(ws + OFF_HIST);
  if (z == 0 && on) ob[0] = 0.f;
  const int t0 = z ? 151 : 1, t1 = z ? 299 : 150;
  for (int tt = t0; tt <= t1; ++tt) {
    const unsigned* hp = (const unsigned*)(hist + ((tt - 1) * 512 + n) * 100);  // uniform -> s_load
    float acc = bias;
#pragma unroll
    for (int q = 0; q < 50; ++q) {
      unsigned u = hp[q];
      acc = fmaf(fw[2*q+0], __half2float(__ushort_as_half((unsigned short)(u & 0xffffu))), acc);
      acc = fmaf(fw[2*q+1], __half2float(__ushort_as_half((unsigned short)(u >> 16))), acc);
    }
    if (on) ob[tt * 50] = acc;
  }
}

extern "C" void kernel_launch(void* const* d_in, const int* in_sizes, int n_in,
                              void* d_out, int out_size, void* d_ws, size_t ws_size,
                              hipStream_t stream) {
  const float* x    = (const float*)d_in[0];
  const float* eWih = (const float*)d_in[1];
  const float* eWhh = (const float*)d_in[2];
  const float* ebih = (const float*)d_in[3];
  const float* ebhh = (const float*)d_in[4];
  const float* dWih = (const float*)d_in[5];
  const float* dWhh = (const float*)d_in[6];
  const float* dbih = (const float*)d_in[7];
  const float* dbhh = (const float*)d_in[8];
  const float* fcW  = (const float*)d_in[9];
  const float* fcb  = (const float*)d_in[10];
  float* out = (float*)d_out;
  float* ws  = (float*)d_ws;

  prep<<<427, 256, 0, stream>>>(dWih, dWhh, dbih, dbhh, eWih, eWhh, ebih, ebhh, fcW, fcb, ws);
  recurrent<<<512, 512, 0, stream>>>(x, ws);
  emit<<<dim3(512, 2), 192, 0, stream>>>(ws, fcb, out);
}

// Round 2
// 1325.438 us; speedup vs baseline: 3.7089x; 3.7089x over previous
//
#include <hip/hip_runtime.h>
#include <hip/hip_fp16.h>

// N=512, C=3, T=300, V=25, M=2, F=150, H=100, gates=4H=400
// x element (n,c,t,v,m) at n*45000 + c*15000 + t*50 + (v*2+m)
// Thread->gate-row map: r(t) = (t&3)*100 + (t>>2), t<400.  (i,f,g,o of cell j adjacent lanes)

// ws layout (float slots):
#define OFF_W2T   0          // [100][512]  dec folded: Whh + Wih@fcW
#define OFF_WDT   51200      // [100][512]  dec Whh (step-1)
#define OFF_WET   102400     // [100][512]  enc Whh
#define OFF_PIH   153600     // [75][512]   enc Wih packed f16 pairs (uint32)
#define OFF_BENC  192000     // [512]
#define OFF_B1    192512     // [512]
#define OFF_BEFF  193024     // [512]
#define OFF_HIST  193536     // ushort hist[512][29952]  (per-n stride padded to 16B mult)
#define HIST_STRIDE 29952    // halfs per sample (299*100 = 29900 used)
#define OFF_XG    7861248    // ushort xg[chunkN][300][400]
// fixed bytes = OFF_XG*4 = 31,444,992; xg bytes = (512/npass)*240000

typedef _Float16 h2_t __attribute__((ext_vector_type(2)));

#if defined(__has_builtin)
#if __has_builtin(__builtin_amdgcn_fdot2)
#define HAS_FDOT2 1
#endif
#endif

__device__ __forceinline__ float fdot2u(unsigned a, unsigned b, float c) {
#ifdef HAS_FDOT2
  return __builtin_amdgcn_fdot2(__builtin_bit_cast(h2_t, a), __builtin_bit_cast(h2_t, b), c, false);
#else
  float al = __half2float(__ushort_as_half((unsigned short)(a & 0xffffu)));
  float ah = __half2float(__ushort_as_half((unsigned short)(a >> 16)));
  float bl = __half2float(__ushort_as_half((unsigned short)(b & 0xffffu)));
  float bh = __half2float(__ushort_as_half((unsigned short)(b >> 16)));
  return fmaf(ah, bh, fmaf(al, bl, c));
#endif
}

__device__ __forceinline__ float fast_sig(float x) {
  float e = __builtin_amdgcn_exp2f(x * -1.442695040888963f);
  return __builtin_amdgcn_rcpf(1.f + e);
}
__device__ __forceinline__ float fast_tanh(float x) {
  float e = __builtin_amdgcn_exp2f(x * -2.885390081777926f);
  return fmaf(2.f, __builtin_amdgcn_rcpf(1.f + e), -1.f);
}

__device__ __forceinline__ float lstm_tail(float acc, int ty, float& c) {
  float v1 = __shfl_xor(acc, 1);
  float v2 = __shfl_xor(acc, 2);
  float v3 = __shfl_xor(v1, 2);
  float d0 = acc;
  float iv = (ty==0)?d0:(ty==1)?v1:(ty==2)?v2:v3;
  float fv = (ty==1)?d0:(ty==0)?v1:(ty==3)?v2:v3;
  float gv = (ty==2)?d0:(ty==3)?v1:(ty==0)?v2:v3;
  float ov = (ty==3)?d0:(ty==2)?v1:(ty==1)?v2:v3;
  float fi = fast_sig(iv), ff = fast_sig(fv), fo = fast_sig(ov);
  float fg = fast_tanh(gv);
  c = fmaf(ff, c, fi * fg);
  return fo * fast_tanh(c);
}

// ---------------- prep: fold decoder weights, transpose to thread-indexed ----------------
__global__ void prep(const float* __restrict__ dWih, const float* __restrict__ dWhh,
                     const float* __restrict__ dbih, const float* __restrict__ dbhh,
                     const float* __restrict__ eWih, const float* __restrict__ eWhh,
                     const float* __restrict__ ebih, const float* __restrict__ ebhh,
                     const float* __restrict__ fcW,  const float* __restrict__ fcb,
                     float* __restrict__ ws)
{
  int idx = blockIdx.x * 256 + threadIdx.x;
  if (idx < 51200) {                       // W2T / WdT / WeT
    int j = idx >> 9, t = idx & 511;
    float w2 = 0.f, wd = 0.f, we = 0.f;
    if (t < 400) {
      int r = (t & 3) * 100 + (t >> 2);
      float s = dWhh[r * 100 + j];
      float acc = 0.f;
      for (int f = 0; f < 150; ++f) acc = fmaf(dWih[r * 150 + f], fcW[f * 100 + j], acc);
      w2 = s + acc; wd = s; we = eWhh[r * 100 + j];
    }
    ws[OFF_W2T + idx] = w2; ws[OFF_WDT + idx] = wd; ws[OFF_WET + idx] = we;
  } else if (idx < 51200 + 38400) {        // packed f16 enc_Wih
    int k = idx - 51200; int d = k >> 9, t = k & 511;
    unsigned pk = 0;
    if (t < 400) {
      int r = (t & 3) * 100 + (t >> 2);
      unsigned lo = __half_as_ushort(__float2half(eWih[r * 150 + 2 * d]));
      unsigned hi = __half_as_ushort(__float2half(eWih[r * 150 + 2 * d + 1]));
      pk = lo | (hi << 16);
    }
    ((unsigned*)ws)[OFF_PIH + k] = pk;
  } else if (idx < 51200 + 38400 + 512) {  // biases
    int t = idx - (51200 + 38400);
    float be = 0.f, b1 = 0.f, bf = 0.f;
    if (t < 400) {
      int r = (t & 3) * 100 + (t >> 2);
      be = ebih[r] + ebhh[r];
      b1 = dbih[r] + dbhh[r];
      float acc = 0.f;
      for (int f = 0; f < 150; ++f) acc = fmaf(dWih[r * 150 + f], fcb[f], acc);
      bf = b1 + acc;
    }
    ws[OFF_BENC + t] = be; ws[OFF_B1 + t] = b1; ws[OFF_BEFF + t] = bf;
  }
}

// ---------------- pre: xg[n][t][g] = enc_Wih(f16) @ x_t, fully parallel ----------------
// block = one sample; x staged in LDS f16 in 2 halves (48 KB -> 2 blocks/CU); wih in ~75 VGPRs
__global__ __launch_bounds__(512, 4)
void pre(const float* __restrict__ x, const float* __restrict__ ws,
         unsigned short* __restrict__ xg, int n0)
{
  const int tid = threadIdx.x;
  const int n = n0 + blockIdx.x;
  __shared__ unsigned short xls[150 * 160];   // rows padded to 160 halfs (320 B)

  unsigned wih[75];
  const unsigned* pih = ((const unsigned*)ws) + OFF_PIH;
#pragma unroll
  for (int d = 0; d < 75; ++d) wih[d] = pih[(d << 9) + tid];

  const float* xb = x + (size_t)n * 45000;
  unsigned short* xgr = xg + (size_t)blockIdx.x * 120000 + ((tid < 400) ? tid : 0);
  const bool on = tid < 400;

  for (int phase = 0; phase < 2; ++phase) {
    const int tbase = phase * 150;
    if (phase) __syncthreads();
    // stage rows tbase..tbase+149 as f16 (pad cols 150..159 zero)
    for (int d = tid; d < 150 * 160; d += 512) {
      int tl = d / 160, f = d - tl * 160;
      float v = 0.f;
      if (f < 150) {
        int c = f / 50, q = f - c * 50;
        v = xb[c * 15000 + (tbase + tl) * 50 + q];
      }
      xls[tl * 160 + f] = __half_as_ushort(__float2half(v));
    }
    __syncthreads();
    if (on) {
      for (int tl = 0; tl < 150; ++tl) {
        const uint4* row = (const uint4*)(xls + tl * 160);
        float a = 0.f;
#pragma unroll
        for (int ch = 0; ch < 18; ++ch) {
          uint4 v = row[ch];
          a = fdot2u(wih[4 * ch + 0], v.x, a);
          a = fdot2u(wih[4 * ch + 1], v.y, a);
          a = fdot2u(wih[4 * ch + 2], v.z, a);
          a = fdot2u(wih[4 * ch + 3], v.w, a);
        }
        uint4 v = row[18];
        a = fdot2u(wih[72], v.x, a);
        a = fdot2u(wih[73], v.y, a);
        a = fdot2u(wih[74], v.z, a);
        xgr[(size_t)(tbase + tl) * 400] = __half_as_ushort(__float2half(a));
      }
    }
  }
}

// ---------------- recurrent: 599 serial steps, only Whh@h per step ----------------
__global__ __launch_bounds__(512, 4)
void recurrent(const unsigned short* __restrict__ xg, float* __restrict__ ws, int n0)
{
  const int t  = threadIdx.x;
  const int n  = n0 + blockIdx.x;
  const int j  = t >> 2, ty = t & 3;
  const bool leader = (t < 400) && (ty == 0);
  __shared__ float hbuf[2][112];

  float whh[100];
#pragma unroll
  for (int k = 0; k < 100; ++k) whh[k] = ws[OFF_WET + (k << 9) + t];

  const float benc  = ws[OFF_BENC + t];
  const float b1g   = ws[OFF_B1   + t];
  const float beffg = ws[OFF_BEFF + t];
  unsigned short* histn = ((unsigned short*)(ws + OFF_HIST)) + (size_t)n * HIST_STRIDE;
  const unsigned short* xgr = xg + (size_t)blockIdx.x * 120000 + ((t < 400) ? t : 0);
  float c = 0.f;

  // encoder: acc = benc + xg + Whh@h ; xg prefetched 2 steps ahead
  unsigned short p0 = xgr[0], p1 = xgr[400];
  for (int ts = 0; ts < 300; ++ts) {
    const int rd = ts & 1, wr = rd ^ 1;
    const int pi = (ts + 2 < 300) ? (ts + 2) : 299;
    unsigned short nx = xgr[(size_t)pi * 400];
    float acc = benc + __half2float(__ushort_as_half(p0));
    if (ts > 0) {
#pragma unroll
      for (int k = 0; k < 100; k += 4) {
        float4 h4 = *(const float4*)&hbuf[rd][k];
        acc = fmaf(whh[k+0], h4.x, acc);
        acc = fmaf(whh[k+1], h4.y, acc);
        acc = fmaf(whh[k+2], h4.z, acc);
        acc = fmaf(whh[k+3], h4.w, acc);
      }
    }
    float hn = lstm_tail(acc, ty, c);
    if (leader) hbuf[wr][j] = hn;
    __syncthreads();
    p0 = p1; p1 = nx;
  }

  // decoder: step 1 plain Whh (input zeros), steps 2.. folded W2
#pragma unroll
  for (int k = 0; k < 100; ++k) whh[k] = ws[OFF_WDT + (k << 9) + t];
  for (int s = 1; s <= 299; ++s) {
    const int rd = (299 + s) & 1, wr = rd ^ 1;
    float acc = (s == 1) ? b1g : beffg;
#pragma unroll
    for (int k = 0; k < 100; k += 4) {
      float4 h4 = *(const float4*)&hbuf[rd][k];
      acc = fmaf(whh[k+0], h4.x, acc);
      acc = fmaf(whh[k+1], h4.y, acc);
      acc = fmaf(whh[k+2], h4.z, acc);
      acc = fmaf(whh[k+3], h4.w, acc);
    }
    float hn = lstm_tail(acc, ty, c);
    if (leader) {
      hbuf[wr][j] = hn;
      histn[(s - 1) * 100 + j] = __half_as_ushort(__float2half(hn));
    }
    __syncthreads();
    if (s == 1) {
#pragma unroll
      for (int k = 0; k < 100; ++k) whh[k] = ws[OFF_W2T + (k << 9) + t];
    }
  }
}

// ---------------- emit: out[n][t] = fcW @ h_{t-1} + fcb; hist staged in LDS ----------------
__global__ __launch_bounds__(192, 4)
void emit(const float* __restrict__ ws, const float* __restrict__ fcW,
          const float* __restrict__ fcb, float* __restrict__ out)
{
  const int f = threadIdx.x;
  const int n = blockIdx.x;
  const int z = blockIdx.y;
  __shared__ unsigned short hl[15008];

  // stage 150 hist rows (15000 halfs) for this (n, z) half
  const uint4* src = (const uint4*)(((const unsigned short*)(ws + OFF_HIST)) +
                                    (size_t)n * HIST_STRIDE + z * 15000);
  for (int k = f; k < 1875; k += 192) ((uint4*)hl)[k] = src[k];

  const bool on = f < 150;
  unsigned fw[50];
  float bias = 0.f;
  if (on) {
    const float* fp = fcW + f * 100;
#pragma unroll
    for (int q = 0; q < 50; ++q) {
      unsigned lo = __half_as_ushort(__float2half(fp[2*q]));
      unsigned hi = __half_as_ushort(__float2half(fp[2*q+1]));
      fw[q] = lo | (hi << 16);
    }
    bias = fcb[f];
  }
  __syncthreads();

  if (!on) return;
  const int cc = f / 50, r = f - cc * 50;
  float* ob = out + (size_t)n * 45000 + cc * 15000 + r;
  if (z == 0) ob[0] = 0.f;
  const int rows = z ? 149 : 150;
  for (int tl = 0; tl < rows; ++tl) {
    const uint4* row = (const uint4*)(hl + tl * 100);
    float acc = bias;
#pragma unroll
    for (int ch = 0; ch < 12; ++ch) {
      uint4 v = row[ch];
      acc = fdot2u(fw[4*ch+0], v.x, acc);
      acc = fdot2u(fw[4*ch+1], v.y, acc);
      acc = fdot2u(fw[4*ch+2], v.z, acc);
      acc = fdot2u(fw[4*ch+3], v.w, acc);
    }
    uint2 v2 = *(const uint2*)(hl + tl * 100 + 96);
    acc = fdot2u(fw[48], v2.x, acc);
    acc = fdot2u(fw[49], v2.y, acc);
    const int tt = z * 150 + tl + 1;
    ob[tt * 50] = acc;
  }
}

extern "C" void kernel_launch(void* const* d_in, const int* in_sizes, int n_in,
                              void* d_out, int out_size, void* d_ws, size_t ws_size,
                              hipStream_t stream) {
  const float* x    = (const float*)d_in[0];
  const float* eWih = (const float*)d_in[1];
  const float* eWhh = (const float*)d_in[2];
  const float* ebih = (const float*)d_in[3];
  const float* ebhh = (const float*)d_in[4];
  const float* dWih = (const float*)d_in[5];
  const float* dWhh = (const float*)d_in[6];
  const float* dbih = (const float*)d_in[7];
  const float* dbhh = (const float*)d_in[8];
  const float* fcW  = (const float*)d_in[9];
  const float* fcb  = (const float*)d_in[10];
  float* out = (float*)d_out;
  float* ws  = (float*)d_ws;

  const size_t fixed_bytes = (size_t)OFF_XG * 4;
  int npass = 1;
  while (npass < 8) {
    size_t need = fixed_bytes + (size_t)(512 / npass) * 300 * 400 * 2;
    if (need <= ws_size) break;
    npass *= 2;
  }
  const int chunk = 512 / npass;
  unsigned short* xg = (unsigned short*)((char*)d_ws + fixed_bytes);

  prep<<<352, 256, 0, stream>>>(dWih, dWhh, dbih, dbhh, eWih, eWhh, ebih, ebhh, fcW, fcb, ws);
  for (int p = 0; p < npass; ++p) {
    pre<<<chunk, 512, 0, stream>>>(x, ws, xg, p * chunk);
    recurrent<<<chunk, 512, 0, stream>>>(xg, ws, p * chunk);
  }
  emit<<<dim3(512, 2), 192, 0, stream>>>(ws, fcW, fcb, out);
}

// Round 3
// 1135.556 us; speedup vs baseline: 4.3291x; 1.1672x over previous
//
#include <hip/hip_runtime.h>
#include <hip/hip_fp16.h>

// N=512, C=3, T=300, V=25, M=2, F=150, H=100, gates=4H=400
// x element (n,c,t,v,m) at n*45000 + c*15000 + t*50 + (v*2+m)
// Thread->gate-row map: r(t) = (t&3)*100 + (t>>2), t<400 (i,f,g,o of cell j on adjacent lanes)

// ws layout (BYTE offsets):
#define B_W2P   0u          // uint[50][512]  dec folded Whh+Wih@fcW, f16-pair packed
#define B_WDP   102400u     // uint[50][512]  dec Whh (step-1)
#define B_WEP   204800u     // uint[50][512]  enc Whh
#define B_PIH   307200u     // uint[75][512]  enc Wih f16 pairs
#define B_BENC  460800u     // float[512]
#define B_B1    462848u     // float[512]
#define B_BEFF  464896u     // float[512]
#define B_HIST  466944u     // ushort hist[512][29952]
#define HIST_STRIDE 29952
#define B_XG    31137792u   // ushort xg[chunkN][300][400]

typedef _Float16 h2_t __attribute__((ext_vector_type(2)));

#if defined(__has_builtin)
#if __has_builtin(__builtin_amdgcn_fdot2)
#define HAS_FDOT2 1
#endif
#endif

__device__ __forceinline__ float fdot2u(unsigned a, unsigned b, float c) {
#ifdef HAS_FDOT2
  return __builtin_amdgcn_fdot2(__builtin_bit_cast(h2_t, a), __builtin_bit_cast(h2_t, b), c, false);
#else
  float al = __half2float(__ushort_as_half((unsigned short)(a & 0xffffu)));
  float ah = __half2float(__ushort_as_half((unsigned short)(a >> 16)));
  float bl = __half2float(__ushort_as_half((unsigned short)(b & 0xffffu)));
  float bh = __half2float(__ushort_as_half((unsigned short)(b >> 16)));
  return fmaf(ah, bh, fmaf(al, bl, c));
#endif
}

__device__ __forceinline__ unsigned pack2f(float a, float b) {
  return (unsigned)__half_as_ushort(__float2half(a)) |
         ((unsigned)__half_as_ushort(__float2half(b)) << 16);
}

__device__ __forceinline__ float fast_sig(float x) {
  float e = __builtin_amdgcn_exp2f(x * -1.442695040888963f);
  return __builtin_amdgcn_rcpf(1.f + e);
}
__device__ __forceinline__ float fast_tanh(float x) {
  float e = __builtin_amdgcn_exp2f(x * -2.885390081777926f);
  return fmaf(2.f, __builtin_amdgcn_rcpf(1.f + e), -1.f);
}

// activate-then-shuffle tail: on leader lanes (ty==0) act=sig(i), v1=sig(f),
// v2=tanh(g), v3=sig(o). Non-leader lanes compute garbage (discarded).
__device__ __forceinline__ float lstm_tail(float acc, int ty, float& c) {
  float sg = fast_sig(acc);
  float th = fast_tanh(acc);
  float act = (ty == 2) ? th : sg;
  float v1 = __shfl_xor(act, 1);
  float v2 = __shfl_xor(act, 2);
  float v3 = __shfl_xor(v1, 2);
  c = fmaf(v1, c, act * v2);
  return v3 * fast_tanh(c);
}

// K=100 f16 dot: 12 uint4 + 1 uint2 LDS reads, 50 fdot2, 4 accumulators
__device__ __forceinline__ float dot100(const unsigned short* hb, const unsigned* wp) {
  const uint4* h4 = (const uint4*)hb;
  float a0 = 0.f, a1 = 0.f, a2 = 0.f, a3 = 0.f;
#pragma unroll
  for (int ch = 0; ch < 12; ++ch) {
    uint4 v = h4[ch];
    a0 = fdot2u(wp[4 * ch + 0], v.x, a0);
    a1 = fdot2u(wp[4 * ch + 1], v.y, a1);
    a2 = fdot2u(wp[4 * ch + 2], v.z, a2);
    a3 = fdot2u(wp[4 * ch + 3], v.w, a3);
  }
  uint2 v2 = *(const uint2*)(hb + 96);
  a0 = fdot2u(wp[48], v2.x, a0);
  a1 = fdot2u(wp[49], v2.y, a1);
  return (a0 + a1) + (a2 + a3);
}

// ---------------- prep ----------------
__global__ void prep(const float* __restrict__ dWih, const float* __restrict__ dWhh,
                     const float* __restrict__ dbih, const float* __restrict__ dbhh,
                     const float* __restrict__ eWih, const float* __restrict__ eWhh,
                     const float* __restrict__ ebih, const float* __restrict__ ebhh,
                     const float* __restrict__ fcW,  const float* __restrict__ fcb,
                     char* __restrict__ wsb)
{
  int idx = blockIdx.x * 256 + threadIdx.x;
  if (idx < 25600) {                       // packed weight rows (pairs)
    int q = idx >> 9, t = idx & 511;
    unsigned w2p = 0, wdp = 0, wep = 0;
    if (t < 400) {
      int r = (t & 3) * 100 + (t >> 2);
      int j0 = 2 * q, j1 = 2 * q + 1;
      float wd0 = dWhh[r * 100 + j0], wd1 = dWhh[r * 100 + j1];
      float we0 = eWhh[r * 100 + j0], we1 = eWhh[r * 100 + j1];
      float s0 = 0.f, s1 = 0.f;
      for (int f = 0; f < 150; ++f) {
        float a = dWih[r * 150 + f];
        s0 = fmaf(a, fcW[f * 100 + j0], s0);
        s1 = fmaf(a, fcW[f * 100 + j1], s1);
      }
      w2p = pack2f(wd0 + s0, wd1 + s1);
      wdp = pack2f(wd0, wd1);
      wep = pack2f(we0, we1);
    }
    ((unsigned*)(wsb + B_W2P))[idx] = w2p;
    ((unsigned*)(wsb + B_WDP))[idx] = wdp;
    ((unsigned*)(wsb + B_WEP))[idx] = wep;
  } else if (idx < 25600 + 38400) {        // packed f16 enc_Wih
    int k = idx - 25600; int d = k >> 9, t = k & 511;
    unsigned pk = 0;
    if (t < 400) {
      int r = (t & 3) * 100 + (t >> 2);
      pk = pack2f(eWih[r * 150 + 2 * d], eWih[r * 150 + 2 * d + 1]);
    }
    ((unsigned*)(wsb + B_PIH))[k] = pk;
  } else if (idx < 25600 + 38400 + 512) {  // biases
    int t = idx - (25600 + 38400);
    float be = 0.f, b1 = 0.f, bf = 0.f;
    if (t < 400) {
      int r = (t & 3) * 100 + (t >> 2);
      be = ebih[r] + ebhh[r];
      b1 = dbih[r] + dbhh[r];
      float acc = 0.f;
      for (int f = 0; f < 150; ++f) acc = fmaf(dWih[r * 150 + f], fcb[f], acc);
      bf = b1 + acc;
    }
    ((float*)(wsb + B_BENC))[t] = be;
    ((float*)(wsb + B_B1))[t]   = b1;
    ((float*)(wsb + B_BEFF))[t] = bf;
  }
}

// ---------------- pre: xg[n][t][g] = enc_Wih(f16) @ x_t ----------------
__global__ __launch_bounds__(512, 4)
void pre(const float* __restrict__ x, const char* __restrict__ wsb,
         unsigned short* __restrict__ xg, int n0)
{
  const int tid = threadIdx.x;
  const int n = n0 + blockIdx.x;
  __shared__ unsigned short xls[150 * 160];

  unsigned wih[75];
  const unsigned* pih = (const unsigned*)(wsb + B_PIH);
#pragma unroll
  for (int d = 0; d < 75; ++d) wih[d] = pih[(d << 9) + tid];

  const float* xb = x + (size_t)n * 45000;
  unsigned short* xgr = xg + (size_t)blockIdx.x * 120000 + ((tid < 400) ? tid : 0);
  const bool on = tid < 400;

  for (int phase = 0; phase < 2; ++phase) {
    const int tbase = phase * 150;
    if (phase) __syncthreads();
    for (int d = tid; d < 150 * 160; d += 512) {
      int tl = d / 160, f = d - tl * 160;
      float v = 0.f;
      if (f < 150) {
        int c = f / 50, q = f - c * 50;
        v = xb[c * 15000 + (tbase + tl) * 50 + q];
      }
      xls[tl * 160 + f] = __half_as_ushort(__float2half(v));
    }
    __syncthreads();
    if (on) {
      for (int tl = 0; tl < 150; ++tl) {
        const uint4* row = (const uint4*)(xls + tl * 160);
        float a0 = 0.f, a1 = 0.f, a2 = 0.f, a3 = 0.f;
#pragma unroll
        for (int ch = 0; ch < 18; ++ch) {
          uint4 v = row[ch];
          a0 = fdot2u(wih[4 * ch + 0], v.x, a0);
          a1 = fdot2u(wih[4 * ch + 1], v.y, a1);
          a2 = fdot2u(wih[4 * ch + 2], v.z, a2);
          a3 = fdot2u(wih[4 * ch + 3], v.w, a3);
        }
        uint4 v = row[18];
        a0 = fdot2u(wih[72], v.x, a0);
        a1 = fdot2u(wih[73], v.y, a1);
        a2 = fdot2u(wih[74], v.z, a2);
        float a = (a0 + a1) + (a2 + a3);
        xgr[(size_t)(tbase + tl) * 400] = __half_as_ushort(__float2half(a));
      }
    }
  }
}

// ---------------- recurrent: 599 serial steps, f16 dot2 path ----------------
__global__ __launch_bounds__(512, 4)
void recurrent(const unsigned short* __restrict__ xg, char* __restrict__ wsb, int n0)
{
  const int t  = threadIdx.x;
  const int n  = n0 + blockIdx.x;
  const int j  = t >> 2, ty = t & 3;
  const bool leader = (t < 400) && (ty == 0);
  __shared__ unsigned short hh[2][112];

  const unsigned* WEP = (const unsigned*)(wsb + B_WEP);
  const unsigned* WDP = (const unsigned*)(wsb + B_WDP);
  const unsigned* W2P = (const unsigned*)(wsb + B_W2P);

  unsigned wp[50];
#pragma unroll
  for (int q = 0; q < 50; ++q) wp[q] = WEP[(q << 9) + t];

  const float benc = ((const float*)(wsb + B_BENC))[t];
  const float b1g  = ((const float*)(wsb + B_B1))[t];
  const float beff = ((const float*)(wsb + B_BEFF))[t];
  unsigned short* histn = (unsigned short*)(wsb + B_HIST) + (size_t)n * HIST_STRIDE;
  const unsigned short* xgr = xg + (size_t)blockIdx.x * 120000 + ((t < 400) ? t : 0);
  float c = 0.f;

  // encoder step 0 (h=0): acc = benc + xg0
  unsigned short p1 = xgr[400];
  {
    float acc = benc + __half2float(__ushort_as_half(xgr[0]));
    float hn = lstm_tail(acc, ty, c);
    if (leader) hh[1][j] = __half_as_ushort(__float2half(hn));
    __syncthreads();
  }
  // encoder steps 1..299
  for (int ts = 1; ts < 300; ++ts) {
    const int rd = ts & 1, wr = rd ^ 1;
    unsigned short pn = xgr[(size_t)((ts + 1 < 300) ? ts + 1 : 299) * 400];
    float acc = benc + __half2float(__ushort_as_half(p1)) + dot100(hh[rd], wp);
    float hn = lstm_tail(acc, ty, c);
    if (leader) hh[wr][j] = __half_as_ushort(__float2half(hn));
    __syncthreads();
    p1 = pn;
  }

  // decoder step 1: plain Whh (input zeros); enc h is in hh[0]
#pragma unroll
  for (int q = 0; q < 50; ++q) wp[q] = WDP[(q << 9) + t];
  {
    float acc = b1g + dot100(hh[0], wp);
    float hn = lstm_tail(acc, ty, c);
    if (leader) {
      hh[1][j] = __half_as_ushort(__float2half(hn));
      histn[j] = __half_as_ushort(__float2half(hn));
    }
    __syncthreads();
  }
  // decoder steps 2..299: folded W2
#pragma unroll
  for (int q = 0; q < 50; ++q) wp[q] = W2P[(q << 9) + t];
  for (int s = 2; s <= 299; ++s) {
    const int rd = (299 + s) & 1, wr = rd ^ 1;
    float acc = beff + dot100(hh[rd], wp);
    float hn = lstm_tail(acc, ty, c);
    if (leader) {
      hh[wr][j] = __half_as_ushort(__float2half(hn));
      histn[(s - 1) * 100 + j] = __half_as_ushort(__float2half(hn));
    }
    __syncthreads();
  }
}

// ---------------- emit: out[n][t] = fcW @ h_{t-1} + fcb ----------------
__global__ __launch_bounds__(192, 4)
void emit(const char* __restrict__ wsb, const float* __restrict__ fcW,
          const float* __restrict__ fcb, float* __restrict__ out)
{
  const int f = threadIdx.x;
  const int n = blockIdx.x;
  const int z = blockIdx.y;
  __shared__ unsigned short hl[15008];

  const uint4* src = (const uint4*)((const unsigned short*)(wsb + B_HIST) +
                                    (size_t)n * HIST_STRIDE + z * 15000);
  for (int k = f; k < 1875; k += 192) ((uint4*)hl)[k] = src[k];

  const bool on = f < 150;
  unsigned fw[50];
  float bias = 0.f;
  if (on) {
    const float* fp = fcW + f * 100;
#pragma unroll
    for (int q = 0; q < 50; ++q) fw[q] = pack2f(fp[2 * q], fp[2 * q + 1]);
    bias = fcb[f];
  }
  __syncthreads();

  if (!on) return;
  const int cc = f / 50, r = f - cc * 50;
  float* ob = out + (size_t)n * 45000 + cc * 15000 + r;
  if (z == 0) ob[0] = 0.f;
  const int rows = z ? 149 : 150;
  for (int tl = 0; tl < rows; ++tl) {
    const uint4* row = (const uint4*)(hl + tl * 100);
    float a0 = bias, a1 = 0.f, a2 = 0.f, a3 = 0.f;
#pragma unroll
    for (int ch = 0; ch < 12; ++ch) {
      uint4 v = row[ch];
      a0 = fdot2u(fw[4 * ch + 0], v.x, a0);
      a1 = fdot2u(fw[4 * ch + 1], v.y, a1);
      a2 = fdot2u(fw[4 * ch + 2], v.z, a2);
      a3 = fdot2u(fw[4 * ch + 3], v.w, a3);
    }
    uint2 v2 = *(const uint2*)(hl + tl * 100 + 96);
    a0 = fdot2u(fw[48], v2.x, a0);
    a1 = fdot2u(fw[49], v2.y, a1);
    const int tt = z * 150 + tl + 1;
    ob[tt * 50] = (a0 + a1) + (a2 + a3);
  }
}

extern "C" void kernel_launch(void* const* d_in, const int* in_sizes, int n_in,
                              void* d_out, int out_size, void* d_ws, size_t ws_size,
                              hipStream_t stream) {
  const float* x    = (const float*)d_in[0];
  const float* eWih = (const float*)d_in[1];
  const float* eWhh = (const float*)d_in[2];
  const float* ebih = (const float*)d_in[3];
  const float* ebhh = (const float*)d_in[4];
  const float* dWih = (const float*)d_in[5];
  const float* dWhh = (const float*)d_in[6];
  const float* dbih = (const float*)d_in[7];
  const float* dbhh = (const float*)d_in[8];
  const float* fcW  = (const float*)d_in[9];
  const float* fcb  = (const float*)d_in[10];
  float* out = (float*)d_out;
  char* wsb  = (char*)d_ws;

  int npass = 1;
  while (npass < 8) {
    size_t need = (size_t)B_XG + (size_t)(512 / npass) * 300 * 400 * 2;
    if (need <= ws_size) break;
    npass *= 2;
  }
  const int chunk = 512 / npass;
  unsigned short* xg = (unsigned short*)(wsb + B_XG);

  prep<<<252, 256, 0, stream>>>(dWih, dWhh, dbih, dbhh, eWih, eWhh, ebih, ebhh, fcW, fcb, wsb);
  for (int p = 0; p < npass; ++p) {
    pre<<<chunk, 512, 0, stream>>>(x, wsb, xg, p * chunk);
    recurrent<<<chunk, 512, 0, stream>>>(xg, wsb, p * chunk);
  }
  emit<<<dim3(512, 2), 192, 0, stream>>>(wsb, fcW, fcb, out);
}